// Round 1
// 954.498 us; speedup vs baseline: 1.2068x; 1.2068x over previous
//
#include <hip/hip_runtime.h>

// ---------------------------------------------------------------------------
// TPUGEMMLinear: blockwise-fp8 quantize (block=128) of x[M,K] (along K) and
// w[K,N] (along N), dequant-scaled fp32 GEMM + bias.
// R1: GEMM rewritten as the 256x256 8-phase template (T1+T2+T3/T4+T5):
//   - 256x256 tile, BK=64, 8 waves (2Mx4N), 512 threads, 128 KiB dbuf LDS
//   - st_16x32 XOR swizzle (byte ^= ((byte>>9)&1)<<5) applied as
//     pre-swizzled GLOBAL source (linear global_load_lds dest) + swizzled
//     ds_read address (both-sides involution)
//   - 8 phases / 2 K-tiles per iter; counted s_waitcnt vmcnt(4)/(6) at
//     phases 4/8 (own issue/drain ledger, never 0 in main loop)
//   - s_setprio(1) around each 16-MFMA cluster
//   - bijective XCD swizzle on flattened blockIdx (nwg=1024 % 8 == 0)
// Quant kernels unchanged from previous round.
// Workspace: Xd bf16 [M*K] | Bt bf16 [N*K]  (160 MB).
// ---------------------------------------------------------------------------

typedef __attribute__((ext_vector_type(8))) short short8;   // 8 x bf16 frag
typedef __attribute__((ext_vector_type(4))) float f32x4;
typedef unsigned short ushort_t;

__device__ __forceinline__ float fp8_round_trip(float v) {
    int p = __builtin_amdgcn_cvt_pk_fp8_f32(v, v, 0, false);
    return __builtin_amdgcn_cvt_f32_fp8(p, 0);
}

__device__ __forceinline__ ushort_t f32_to_bf16(float f) {
    union { float f; unsigned u; } un; un.f = f;
    unsigned r = un.u + 0x7fffu + ((un.u >> 16) & 1u);
    return (ushort_t)(r >> 16);
}

// async 16B/lane global -> LDS (wave-uniform LDS base + lane*16)
__device__ __forceinline__ void async16(const void* g, void* l) {
    __builtin_amdgcn_global_load_lds(
        (const __attribute__((address_space(1))) unsigned int*)g,
        (__attribute__((address_space(3))) unsigned int*)l,
        16, 0, 0);
}

// ---------------------------------------------------------------------------
// quant_x: x[M,K] f32 -> Xd[M,K] bf16 (dequantized). One 128-elem fp8 block
// per 32-lane half-wave; each lane handles one float4 (4 elems).
// ---------------------------------------------------------------------------
__global__ __launch_bounds__(256) void quant_x_kernel(
        const float* __restrict__ x, ushort_t* __restrict__ xd) {
    size_t tid  = (size_t)blockIdx.x * 256 + threadIdx.x;
    size_t base = tid * 4;
    float4 v = *(const float4*)(x + base);
    float amax = fmaxf(fmaxf(fabsf(v.x), fabsf(v.y)),
                       fmaxf(fabsf(v.z), fabsf(v.w)));
    #pragma unroll
    for (int m = 1; m < 32; m <<= 1)
        amax = fmaxf(amax, __shfl_xor(amax, m, 64));
    float scale = fmaxf(amax / 448.0f, 1e-12f);
    ushort4 o;
    o.x = f32_to_bf16(fp8_round_trip(v.x / scale) * scale);
    o.y = f32_to_bf16(fp8_round_trip(v.y / scale) * scale);
    o.z = f32_to_bf16(fp8_round_trip(v.z / scale) * scale);
    o.w = f32_to_bf16(fp8_round_trip(v.w / scale) * scale);
    *(ushort4*)(xd + base) = o;
}

// ---------------------------------------------------------------------------
// quant_w: w[K,N] f32 -> Bt[N,K] bf16 (dequantized + transposed).
// ---------------------------------------------------------------------------
__global__ __launch_bounds__(256) void quant_w_kernel(
        const float* __restrict__ w, ushort_t* __restrict__ bt,
        int K, int N) {
    __shared__ float lds[128 * 65];
    int k0 = blockIdx.x * 64;
    int n0 = blockIdx.y * 128;
    int t = threadIdx.x;
    int wid = t >> 6, lane = t & 63;
    int half = lane >> 5, l32 = lane & 31;

    #pragma unroll
    for (int rr = 0; rr < 8; ++rr) {
        int klocal = wid * 16 + rr * 2 + half;
        int k = k0 + klocal;
        float4 v = *(const float4*)(w + (size_t)k * N + n0 + l32 * 4);
        float amax = fmaxf(fmaxf(fabsf(v.x), fabsf(v.y)),
                           fmaxf(fabsf(v.z), fabsf(v.w)));
        #pragma unroll
        for (int m = 1; m < 32; m <<= 1)
            amax = fmaxf(amax, __shfl_xor(amax, m, 64));
        float scale = fmaxf(amax / 448.0f, 1e-12f);
        int nl = l32 * 4;
        lds[(nl + 0) * 65 + klocal] = fp8_round_trip(v.x / scale) * scale;
        lds[(nl + 1) * 65 + klocal] = fp8_round_trip(v.y / scale) * scale;
        lds[(nl + 2) * 65 + klocal] = fp8_round_trip(v.z / scale) * scale;
        lds[(nl + 3) * 65 + klocal] = fp8_round_trip(v.w / scale) * scale;
    }
    __syncthreads();
    #pragma unroll
    for (int it = 0; it < 8; ++it) {
        int idx = it * 256 + t;
        int j = idx >> 4;
        int c = idx & 15;
        const float* p = &lds[j * 65 + c * 4];
        ushort4 o;
        o.x = f32_to_bf16(p[0]);
        o.y = f32_to_bf16(p[1]);
        o.z = f32_to_bf16(p[2]);
        o.w = f32_to_bf16(p[3]);
        *(ushort4*)(bt + (size_t)(n0 + j) * K + k0 + c * 4) = o;
    }
}

// ---------------------------------------------------------------------------
// gemm256: C[M,N] = A[M,K](bf16) * Bt[N,K](bf16)^T + bias.
// 256x256 tile, BK=64, 512 threads = 8 waves (wr=wid>>2 in {0,1} x wcn=wid&3
// in {0..3}); per-wave output 128x64 = acc[8][4] f32x4.
// LDS: sm[buf][A/B][256*64] bf16, double buffered = 128 KiB.
//
// Swizzle (st_16x32): logical tile byte y (= row*128 + col) is stored at
// LDS byte y ^ (((y>>9)&1)<<5) == row*128 + (col ^ (((row>>2)&1)<<5)).
// Staged via linear LDS dest + pre-swizzled per-lane GLOBAL source; read
// with the same XOR on the ds_read address (involution).
//
// Phase schedule per iteration (2 K-tiles T=2i in buf0, T+1 in buf1):
//  p1: read B01+A0(T)   [12 ds]  | stage (T+1)Bh1 -> buf1 | Q0 acc[0-3][0-1]
//  p2: read A1(T)       [ 8 ds]  |                        | Q1 acc[4-7][0-1]
//  p3: read B23(T)      [ 4 ds]  | stage (T+2)Ah0 -> buf0 | Q2 acc[0-3][2-3]
//  p4:                           | stage (T+2)Ah1, vmcnt(4)| Q3 acc[4-7][2-3]
//  p5: read B01+A0(T+1) [12 ds]  | stage (T+2)Bh0 -> buf0 | Q0
//  p6: read A1(T+1)     [ 8 ds]  | stage (T+2)Bh1 -> buf0 | Q1
//  p7: read B23(T+1)    [ 4 ds]  | stage (T+3)Ah0 -> buf1 | Q2
//  p8:                           | stage (T+3)Ah1+Bh0, vmcnt(6) | Q3
// WAR safety: A-halves of a tile are last ds_read in p2 (p6), B-halves in
// p3 (p7); every overwrite slot above is >= one trailing barrier later.
// Drain ledger (2 loads/half): enter iter with 6 outstanding (next tile's
// Ah0,Ah1,Bh0); vmcnt(4)@p4 completes tile T+1; vmcnt(6)@p8 completes T+2.
// ---------------------------------------------------------------------------

#define GBAR()    asm volatile("s_barrier" ::: "memory")
#define WAITL(n)  asm volatile("s_waitcnt lgkmcnt(" #n ")" ::: "memory")
#define WAITV(n)  asm volatile("s_waitcnt vmcnt(" #n ")" ::: "memory")

#define STAGE_A(h, kt, buf) do {                                             \
    const ushort_t* g_ = aSrc + (size_t)((h) * 128) * K + (size_t)(kt) * 64; \
    ushort_t* l_ = &sm[buf][0][(h) * 8192] + wid * 512;                      \
    async16(g_, l_);                                                         \
    async16(g_ + (size_t)64 * K, l_ + 4096);                                 \
} while (0)

#define STAGE_B(h, kt, buf) do {                                             \
    const ushort_t* g_ = bSrc + (size_t)((h) * 128) * K + (size_t)(kt) * 64; \
    ushort_t* l_ = &sm[buf][1][(h) * 8192] + wid * 512;                      \
    async16(g_, l_);                                                         \
    async16(g_ + (size_t)64 * K, l_ + 4096);                                 \
} while (0)

// A frags: dst[m][ks] = rows wr*128 + (hsel*64 + m*16) + l16, k-slice ks
#define LDA_(dst, buf, hsel) do {                                            \
    const char* p_ = smA[buf] + aOff + (hsel) * 8192;                        \
    _Pragma("unroll") for (int m_ = 0; m_ < 4; ++m_) {                       \
        dst[m_][0] = *(const short8*)(p_ + m_ * 2048);                       \
        dst[m_][1] = *(const short8*)(p_ + m_ * 2048 + 64);                  \
    }                                                                        \
} while (0)

// B frags: bb[n][ks] = rows wcn*64 + (nsel*32 + n*16) + l16
#define LDB_(buf, nsel) do {                                                 \
    const char* p_ = smB[buf] + bOff + (nsel) * 4096;                        \
    _Pragma("unroll") for (int n_ = 0; n_ < 2; ++n_) {                       \
        bb[n_][0] = *(const short8*)(p_ + n_ * 2048);                        \
        bb[n_][1] = *(const short8*)(p_ + n_ * 2048 + 64);                   \
    }                                                                        \
} while (0)

#define MFMAQ(AS, mb, nb) do {                                               \
    _Pragma("unroll") for (int m_ = 0; m_ < 4; ++m_)                         \
    _Pragma("unroll") for (int n_ = 0; n_ < 2; ++n_) {                       \
        acc[(mb) + m_][(nb) + n_] = __builtin_amdgcn_mfma_f32_16x16x32_bf16( \
            AS[m_][0], bb[n_][0], acc[(mb) + m_][(nb) + n_], 0, 0, 0);       \
        acc[(mb) + m_][(nb) + n_] = __builtin_amdgcn_mfma_f32_16x16x32_bf16( \
            AS[m_][1], bb[n_][1], acc[(mb) + m_][(nb) + n_], 0, 0, 0);       \
    }                                                                        \
} while (0)

#define PH_TOP()  GBAR(); WAITL(0); __builtin_amdgcn_sched_barrier(0);       \
                  __builtin_amdgcn_s_setprio(1)
#define PH_END()  __builtin_amdgcn_s_setprio(0); GBAR()

__global__ __launch_bounds__(512, 2) void gemm256_kernel(
        const ushort_t* __restrict__ A, const ushort_t* __restrict__ B,
        const float* __restrict__ bias, float* __restrict__ C,
        int M, int N, int K) {
    __shared__ ushort_t sm[2][2][16384];   // 128 KiB

    const int t = threadIdx.x;
    const int wid = t >> 6;
    const int lane = t & 63;
    const int quad = lane >> 4, l16 = lane & 15;
    const int wr = wid >> 2, wcn = wid & 3;

    // T1: XCD-aware swizzle on flattened block id (nwg = 1024, % 8 == 0)
    const int nwg = gridDim.x;
    const int bid = blockIdx.x;
    int wg = bid;
    if ((nwg & 7) == 0) { const int cpx = nwg >> 3; wg = (bid & 7) * cpx + (bid >> 3); }
    const int nbn = N >> 8;
    const int bm = wg / nbn, bn = wg % nbn;

    // staging: thread t covers 16B at logical tile byte (t>>3)*128+(t&7)*16
    // (per 64-row statement); pre-swizzled global col = col ^ ((t>>5 & 1)<<5)
    const int srow = t >> 3;
    const int scol = ((((t & 7) * 16) ^ (((t >> 5) & 1) << 5)) >> 1); // ushorts
    const ushort_t* aSrc = A + (size_t)(bm * 256 + srow) * K + scol;
    const ushort_t* bSrc = B + (size_t)(bn * 256 + srow) * K + scol;

    // ds_read addressing: tbase = l16*128 + (quad*16 ^ xr), xr from row bit2
    const int xr = ((l16 >> 2) & 1) << 5;
    const int tbase = l16 * 128 + ((quad * 16) ^ xr);
    const int aOff = wr * 16384 + tbase;     // bytes within A tile
    const int bOff = wcn * 8192 + tbase;     // bytes within B tile
    const char* smA[2] = { (const char*)sm[0][0], (const char*)sm[1][0] };
    const char* smB[2] = { (const char*)sm[0][1], (const char*)sm[1][1] };

    f32x4 acc[8][4] = {};
    short8 a0[4][2], a1[4][2], bb[2][2];

    const int NT = K >> 6;     // K-tiles (64)
    const int NI = NT >> 1;    // iterations (32)

    // prologue: tile0 (4 halves) + tile1 Ah0,Ah1,Bh0 = 14 loads; drain tile0
    STAGE_A(0, 0, 0); STAGE_A(1, 0, 0); STAGE_B(0, 0, 0); STAGE_B(1, 0, 0);
    STAGE_A(0, 1, 1); STAGE_A(1, 1, 1); STAGE_B(0, 1, 1);
    WAITV(6); GBAR();

    for (int i = 0; i < NI; ++i) {
        const int T  = 2 * i;
        const int t1 = T + 1;
        const int t2 = (T + 2 < NT) ? T + 2 : 0;   // clamped: re-stages tile0,
        const int t3 = (T + 3 < NT) ? T + 3 : 0;   // never computed

        // ---- phase 1
        LDB_(0, 0); LDA_(a0, 0, 0);
        STAGE_B(1, t1, 1);
        WAITL(8);
        PH_TOP(); MFMAQ(a0, 0, 0); PH_END();
        // ---- phase 2
        LDA_(a1, 0, 1);
        PH_TOP(); MFMAQ(a1, 4, 0); PH_END();
        // ---- phase 3
        LDB_(0, 1);
        STAGE_A(0, t2, 0);
        PH_TOP(); MFMAQ(a0, 0, 2); PH_END();
        // ---- phase 4
        STAGE_A(1, t2, 0);
        WAITV(4);
        GBAR(); __builtin_amdgcn_s_setprio(1); MFMAQ(a1, 4, 2); PH_END();
        // ---- phase 5
        LDB_(1, 0); LDA_(a0, 1, 0);
        STAGE_B(0, t2, 0);
        WAITL(8);
        PH_TOP(); MFMAQ(a0, 0, 0); PH_END();
        // ---- phase 6
        LDA_(a1, 1, 1);
        STAGE_B(1, t2, 0);
        PH_TOP(); MFMAQ(a1, 4, 0); PH_END();
        // ---- phase 7
        LDB_(1, 1);
        STAGE_A(0, t3, 1);
        PH_TOP(); MFMAQ(a0, 0, 2); PH_END();
        // ---- phase 8
        STAGE_A(1, t3, 1);
        STAGE_B(0, t3, 1);
        WAITV(6);
        GBAR(); __builtin_amdgcn_s_setprio(1); MFMAQ(a1, 4, 2); PH_END();
    }

    // epilogue: C/D layout col = lane&15, row = quad*4 + reg (m89/m91)
    #pragma unroll
    for (int nt = 0; nt < 4; ++nt) {
        const int col = bn * 256 + wcn * 64 + nt * 16 + l16;
        const float bv = bias[col];
        #pragma unroll
        for (int mt = 0; mt < 8; ++mt) {
            const int row0 = bm * 256 + wr * 128 + mt * 16 + quad * 4;
            #pragma unroll
            for (int r = 0; r < 4; ++r)
                C[(size_t)(row0 + r) * N + col] = acc[mt][nt][r] + bv;
        }
    }
}

// ---------------------------------------------------------------------------
extern "C" void kernel_launch(void* const* d_in, const int* in_sizes, int n_in,
                              void* d_out, int out_size, void* d_ws, size_t ws_size,
                              hipStream_t stream) {
    const float* x    = (const float*)d_in[0];
    const float* w    = (const float*)d_in[1];
    const float* bias = (const float*)d_in[2];
    float* out = (float*)d_out;

    const int N = in_sizes[2];              // 4096
    const int K = in_sizes[1] / N;          // 4096
    const int M = in_sizes[0] / K;          // 16384

    ushort_t* xd = (ushort_t*)d_ws;                  // M*K bf16
    ushort_t* bt = xd + (size_t)M * K;               // N*K bf16
    // requires ws_size >= (M*K + N*K)*2 = 160 MB

    quant_x_kernel<<<(size_t)M * K / 1024, 256, 0, stream>>>(x, xd);
    quant_w_kernel<<<dim3(K / 64, N / 128), 256, 0, stream>>>(w, bt, K, N);
    gemm256_kernel<<<dim3((M / 256) * (N / 256)), 512, 0, stream>>>(
        xd, bt, bias, out, M, N, K);
}

// Round 3
// 925.611 us; speedup vs baseline: 1.2445x; 1.0312x over previous
//
#include <hip/hip_runtime.h>

// ---------------------------------------------------------------------------
// TPUGEMMLinear: blockwise-fp8 quantize (block=128) of x[M,K] (along K) and
// w[K,N] (along N), dequant-scaled fp32 GEMM + bias.
// R3 == R2 resubmitted (R2 bench died to container infra failure; kernel diff
// audited deadlock/OOB-free, so re-measure unchanged).
// R2: fix the LDS swizzle. R1's 1-bit XOR was a no-op: rows are 128 B = 32
// banks, so all 16 l16-lanes of a quad hit one 4-bank group (16-way).
// New swizzle: byte ^= (row&7)<<4  (Guideline-4 recipe) -> bank start =
// 4*(quad ^ (l16&7)): 8 groups x 8 lanes, balanced, conflict-free.
// Consequence: k-slice-1 (bytes 64..127) addressing must XOR, not add 64:
// cs0/cs1 = (quad*16 + {0,64}) ^ ((l16&7)<<4). Staging pre-swizzles the
// per-lane GLOBAL column with the same involution; LDS dest stays linear.
// Also: quant_x v2 (8 elems/lane, 2 coalesced float4 streams/wave).
// Workspace: Xd bf16 [M*K] | Bt bf16 [N*K]  (160 MB).
// ---------------------------------------------------------------------------

typedef __attribute__((ext_vector_type(8))) short short8;   // 8 x bf16 frag
typedef __attribute__((ext_vector_type(4))) float f32x4;
typedef unsigned short ushort_t;

__device__ __forceinline__ float fp8_round_trip(float v) {
    int p = __builtin_amdgcn_cvt_pk_fp8_f32(v, v, 0, false);
    return __builtin_amdgcn_cvt_f32_fp8(p, 0);
}

__device__ __forceinline__ ushort_t f32_to_bf16(float f) {
    union { float f; unsigned u; } un; un.f = f;
    unsigned r = un.u + 0x7fffu + ((un.u >> 16) & 1u);
    return (ushort_t)(r >> 16);
}

// async 16B/lane global -> LDS (wave-uniform LDS base + lane*16)
__device__ __forceinline__ void async16(const void* g, void* l) {
    __builtin_amdgcn_global_load_lds(
        (const __attribute__((address_space(1))) unsigned int*)g,
        (__attribute__((address_space(3))) unsigned int*)l,
        16, 0, 0);
}

// ---------------------------------------------------------------------------
// quant_x v2: x[M,K] f32 -> Xd[M,K] bf16 (dequantized). Each wave handles
// 512 consecutive elems as two coalesced float4 streams (lane*4 and
// 256+lane*4); each 32-lane half-wave owns one 128-elem fp8 block per
// stream. Halves wave count vs v1, doubles load-level parallelism.
// ---------------------------------------------------------------------------
__global__ __launch_bounds__(256) void quant_x_kernel(
        const float* __restrict__ x, ushort_t* __restrict__ xd) {
    size_t tid  = (size_t)blockIdx.x * 256 + threadIdx.x;
    int lane = threadIdx.x & 63;
    size_t wbase = (tid >> 6) * 512;
    size_t i0 = wbase + (size_t)lane * 4;
    size_t i1 = i0 + 256;
    float4 v0 = *(const float4*)(x + i0);
    float4 v1 = *(const float4*)(x + i1);
    float a0 = fmaxf(fmaxf(fabsf(v0.x), fabsf(v0.y)),
                     fmaxf(fabsf(v0.z), fabsf(v0.w)));
    float a1 = fmaxf(fmaxf(fabsf(v1.x), fabsf(v1.y)),
                     fmaxf(fabsf(v1.z), fabsf(v1.w)));
    #pragma unroll
    for (int m = 1; m < 32; m <<= 1) {
        a0 = fmaxf(a0, __shfl_xor(a0, m, 64));
        a1 = fmaxf(a1, __shfl_xor(a1, m, 64));
    }
    float s0 = fmaxf(a0 / 448.0f, 1e-12f);
    float s1 = fmaxf(a1 / 448.0f, 1e-12f);
    ushort4 o0, o1;
    o0.x = f32_to_bf16(fp8_round_trip(v0.x / s0) * s0);
    o0.y = f32_to_bf16(fp8_round_trip(v0.y / s0) * s0);
    o0.z = f32_to_bf16(fp8_round_trip(v0.z / s0) * s0);
    o0.w = f32_to_bf16(fp8_round_trip(v0.w / s0) * s0);
    o1.x = f32_to_bf16(fp8_round_trip(v1.x / s1) * s1);
    o1.y = f32_to_bf16(fp8_round_trip(v1.y / s1) * s1);
    o1.z = f32_to_bf16(fp8_round_trip(v1.z / s1) * s1);
    o1.w = f32_to_bf16(fp8_round_trip(v1.w / s1) * s1);
    *(ushort4*)(xd + i0) = o0;
    *(ushort4*)(xd + i1) = o1;
}

// ---------------------------------------------------------------------------
// quant_w: w[K,N] f32 -> Bt[N,K] bf16 (dequantized + transposed). Unchanged.
// ---------------------------------------------------------------------------
__global__ __launch_bounds__(256) void quant_w_kernel(
        const float* __restrict__ w, ushort_t* __restrict__ bt,
        int K, int N) {
    __shared__ float lds[128 * 65];
    int k0 = blockIdx.x * 64;
    int n0 = blockIdx.y * 128;
    int t = threadIdx.x;
    int wid = t >> 6, lane = t & 63;
    int half = lane >> 5, l32 = lane & 31;

    #pragma unroll
    for (int rr = 0; rr < 8; ++rr) {
        int klocal = wid * 16 + rr * 2 + half;
        int k = k0 + klocal;
        float4 v = *(const float4*)(w + (size_t)k * N + n0 + l32 * 4);
        float amax = fmaxf(fmaxf(fabsf(v.x), fabsf(v.y)),
                           fmaxf(fabsf(v.z), fabsf(v.w)));
        #pragma unroll
        for (int m = 1; m < 32; m <<= 1)
            amax = fmaxf(amax, __shfl_xor(amax, m, 64));
        float scale = fmaxf(amax / 448.0f, 1e-12f);
        int nl = l32 * 4;
        lds[(nl + 0) * 65 + klocal] = fp8_round_trip(v.x / scale) * scale;
        lds[(nl + 1) * 65 + klocal] = fp8_round_trip(v.y / scale) * scale;
        lds[(nl + 2) * 65 + klocal] = fp8_round_trip(v.z / scale) * scale;
        lds[(nl + 3) * 65 + klocal] = fp8_round_trip(v.w / scale) * scale;
    }
    __syncthreads();
    #pragma unroll
    for (int it = 0; it < 8; ++it) {
        int idx = it * 256 + t;
        int j = idx >> 4;
        int c = idx & 15;
        const float* p = &lds[j * 65 + c * 4];
        ushort4 o;
        o.x = f32_to_bf16(p[0]);
        o.y = f32_to_bf16(p[1]);
        o.z = f32_to_bf16(p[2]);
        o.w = f32_to_bf16(p[3]);
        *(ushort4*)(bt + (size_t)(n0 + j) * K + k0 + c * 4) = o;
    }
}

// ---------------------------------------------------------------------------
// gemm256: C[M,N] = A[M,K](bf16) * Bt[N,K](bf16)^T + bias.
// 256x256 tile, BK=64, 512 threads = 8 waves (wr in {0,1} x wcn in {0..3});
// per-wave output 128x64 = acc[8][4] f32x4. LDS dbuf 128 KiB.
//
// Swizzle: logical tile byte (row, col) stored at LDS byte
// row*128 + (col ^ ((row&7)<<4)). Write side: linear global_load_lds dest
// + pre-swizzled per-lane global column (involution). Read side: lane
// (quad,l16) reads k-slices at cs{0,1} = (quad*16 + {0,64}) ^ ((l16&7)<<4).
// Bank check: start bank = 4*(quad ^ (l16&7)) -> 8 groups x 8 lanes x 16 B
// = balanced minimum-cycle ds_read_b128.
//
// Phase schedule per iteration (2 K-tiles T=2i in buf0, T+1 in buf1):
//  p1: read B01+A0(T)   [12 ds]  | stage (T+1)Bh1 -> buf1 | Q0 acc[0-3][0-1]
//  p2: read A1(T)       [ 8 ds]  |                        | Q1 acc[4-7][0-1]
//  p3: read B23(T)      [ 4 ds]  | stage (T+2)Ah0 -> buf0 | Q2 acc[0-3][2-3]
//  p4:                           | stage (T+2)Ah1, vmcnt(4)| Q3 acc[4-7][2-3]
//  p5: read B01+A0(T+1) [12 ds]  | stage (T+2)Bh0 -> buf0 | Q0
//  p6: read A1(T+1)     [ 8 ds]  | stage (T+2)Bh1 -> buf0 | Q1
//  p7: read B23(T+1)    [ 4 ds]  | stage (T+3)Ah0 -> buf1 | Q2
//  p8:                           | stage (T+3)Ah1+Bh0, vmcnt(6) | Q3
// WAR safety: A-halves last ds_read in p2 (p6), B-halves in p3 (p7); every
// overwrite slot is >= one trailing barrier later. Drain ledger (2 loads per
// half): enter iter with 6 outstanding; vmcnt(4)@p4 completes tile T+1;
// vmcnt(6)@p8 completes T+2.
// ---------------------------------------------------------------------------

#define GBAR()    asm volatile("s_barrier" ::: "memory")
#define WAITL(n)  asm volatile("s_waitcnt lgkmcnt(" #n ")" ::: "memory")
#define WAITV(n)  asm volatile("s_waitcnt vmcnt(" #n ")" ::: "memory")

#define STAGE_A(h, kt, buf) do {                                             \
    const ushort_t* g_ = aSrc + (size_t)((h) * 128) * K + (size_t)(kt) * 64; \
    ushort_t* l_ = &sm[buf][0][(h) * 8192] + wid * 512;                      \
    async16(g_, l_);                                                         \
    async16(g_ + (size_t)64 * K, l_ + 4096);                                 \
} while (0)

#define STAGE_B(h, kt, buf) do {                                             \
    const ushort_t* g_ = bSrc + (size_t)((h) * 128) * K + (size_t)(kt) * 64; \
    ushort_t* l_ = &sm[buf][1][(h) * 8192] + wid * 512;                      \
    async16(g_, l_);                                                         \
    async16(g_ + (size_t)64 * K, l_ + 4096);                                 \
} while (0)

// A frags: dst[m][ks] = rows wr*128 + hsel*64 + m*16 + l16, k-slice cs0/cs1
#define LDA_(dst, buf, hsel) do {                                            \
    const char* p_ = smA[buf] + aBase + (hsel) * 8192;                       \
    _Pragma("unroll") for (int m_ = 0; m_ < 4; ++m_) {                       \
        dst[m_][0] = *(const short8*)(p_ + m_ * 2048 + cs0);                 \
        dst[m_][1] = *(const short8*)(p_ + m_ * 2048 + cs1);                 \
    }                                                                        \
} while (0)

// B frags: bb[n][ks] = rows wcn*64 + nsel*32 + n*16 + l16
#define LDB_(buf, nsel) do {                                                 \
    const char* p_ = smB[buf] + bBase + (nsel) * 4096;                       \
    _Pragma("unroll") for (int n_ = 0; n_ < 2; ++n_) {                       \
        bb[n_][0] = *(const short8*)(p_ + n_ * 2048 + cs0);                  \
        bb[n_][1] = *(const short8*)(p_ + n_ * 2048 + cs1);                  \
    }                                                                        \
} while (0)

#define MFMAQ(AS, mb, nb) do {                                               \
    _Pragma("unroll") for (int m_ = 0; m_ < 4; ++m_)                         \
    _Pragma("unroll") for (int n_ = 0; n_ < 2; ++n_) {                       \
        acc[(mb) + m_][(nb) + n_] = __builtin_amdgcn_mfma_f32_16x16x32_bf16( \
            AS[m_][0], bb[n_][0], acc[(mb) + m_][(nb) + n_], 0, 0, 0);       \
        acc[(mb) + m_][(nb) + n_] = __builtin_amdgcn_mfma_f32_16x16x32_bf16( \
            AS[m_][1], bb[n_][1], acc[(mb) + m_][(nb) + n_], 0, 0, 0);       \
    }                                                                        \
} while (0)

#define PH_TOP()  GBAR(); WAITL(0); __builtin_amdgcn_sched_barrier(0);       \
                  __builtin_amdgcn_s_setprio(1)
#define PH_END()  __builtin_amdgcn_s_setprio(0); GBAR()

__global__ __launch_bounds__(512, 2) void gemm256_kernel(
        const ushort_t* __restrict__ A, const ushort_t* __restrict__ B,
        const float* __restrict__ bias, float* __restrict__ C,
        int M, int N, int K) {
    __shared__ ushort_t sm[2][2][16384];   // 128 KiB

    const int t = threadIdx.x;
    const int wid = t >> 6;
    const int lane = t & 63;
    const int quad = lane >> 4, l16 = lane & 15;
    const int wr = wid >> 2, wcn = wid & 3;

    // T1: XCD-aware swizzle on flattened block id (nwg = 1024, % 8 == 0)
    const int nwg = gridDim.x;
    const int bid = blockIdx.x;
    int wg = bid;
    if ((nwg & 7) == 0) { const int cpx = nwg >> 3; wg = (bid & 7) * cpx + (bid >> 3); }
    const int nbn = N >> 8;
    const int bm = wg / nbn, bn = wg % nbn;

    // staging: thread t covers LDS linear byte t*16 per 64-row statement:
    // row = t>>3, col = (t&7)*16. Pre-swizzled global col = col ^ ((row&7)<<4).
    const int srow = t >> 3;
    const int scol = ((((t & 7) * 16) ^ (((t >> 3) & 7) << 4)) >> 1); // ushorts
    const ushort_t* aSrc = A + (size_t)(bm * 256 + srow) * K + scol;
    const ushort_t* bSrc = B + (size_t)(bn * 256 + srow) * K + scol;

    // ds_read addressing: row base l16*128; k-slice cols XOR-swizzled by row
    const int xr4 = (l16 & 7) << 4;
    const int cs0 = (quad * 16) ^ xr4;
    const int cs1 = (quad * 16 + 64) ^ xr4;
    const int aBase = wr * 16384 + l16 * 128;    // bytes within A tile
    const int bBase = wcn * 8192 + l16 * 128;    // bytes within B tile
    const char* smA[2] = { (const char*)sm[0][0], (const char*)sm[1][0] };
    const char* smB[2] = { (const char*)sm[0][1], (const char*)sm[1][1] };

    f32x4 acc[8][4] = {};
    short8 a0[4][2], a1[4][2], bb[2][2];

    const int NT = K >> 6;     // K-tiles (64)
    const int NI = NT >> 1;    // iterations (32)

    // prologue: tile0 (4 halves) + tile1 Ah0,Ah1,Bh0 = 14 loads; drain tile0
    STAGE_A(0, 0, 0); STAGE_A(1, 0, 0); STAGE_B(0, 0, 0); STAGE_B(1, 0, 0);
    STAGE_A(0, 1, 1); STAGE_A(1, 1, 1); STAGE_B(0, 1, 1);
    WAITV(6); GBAR();

    for (int i = 0; i < NI; ++i) {
        const int T  = 2 * i;
        const int t1 = T + 1;
        const int t2 = (T + 2 < NT) ? T + 2 : 0;   // clamped: re-stages tile0,
        const int t3 = (T + 3 < NT) ? T + 3 : 0;   // never computed

        // ---- phase 1
        LDB_(0, 0); LDA_(a0, 0, 0);
        STAGE_B(1, t1, 1);
        WAITL(8);
        PH_TOP(); MFMAQ(a0, 0, 0); PH_END();
        // ---- phase 2
        LDA_(a1, 0, 1);
        PH_TOP(); MFMAQ(a1, 4, 0); PH_END();
        // ---- phase 3
        LDB_(0, 1);
        STAGE_A(0, t2, 0);
        PH_TOP(); MFMAQ(a0, 0, 2); PH_END();
        // ---- phase 4
        STAGE_A(1, t2, 0);
        WAITV(4);
        GBAR(); __builtin_amdgcn_s_setprio(1); MFMAQ(a1, 4, 2); PH_END();
        // ---- phase 5
        LDB_(1, 0); LDA_(a0, 1, 0);
        STAGE_B(0, t2, 0);
        WAITL(8);
        PH_TOP(); MFMAQ(a0, 0, 0); PH_END();
        // ---- phase 6
        LDA_(a1, 1, 1);
        STAGE_B(1, t2, 0);
        PH_TOP(); MFMAQ(a1, 4, 0); PH_END();
        // ---- phase 7
        LDB_(1, 1);
        STAGE_A(0, t3, 1);
        PH_TOP(); MFMAQ(a0, 0, 2); PH_END();
        // ---- phase 8
        STAGE_A(1, t3, 1);
        STAGE_B(0, t3, 1);
        WAITV(6);
        GBAR(); __builtin_amdgcn_s_setprio(1); MFMAQ(a1, 4, 2); PH_END();
    }

    // epilogue: C/D layout col = lane&15, row = quad*4 + reg (m89/m91)
    #pragma unroll
    for (int nt = 0; nt < 4; ++nt) {
        const int col = bn * 256 + wcn * 64 + nt * 16 + l16;
        const float bv = bias[col];
        #pragma unroll
        for (int mt = 0; mt < 8; ++mt) {
            const int row0 = bm * 256 + wr * 128 + mt * 16 + quad * 4;
            #pragma unroll
            for (int r = 0; r < 4; ++r)
                C[(size_t)(row0 + r) * N + col] = acc[mt][nt][r] + bv;
        }
    }
}

// ---------------------------------------------------------------------------
extern "C" void kernel_launch(void* const* d_in, const int* in_sizes, int n_in,
                              void* d_out, int out_size, void* d_ws, size_t ws_size,
                              hipStream_t stream) {
    const float* x    = (const float*)d_in[0];
    const float* w    = (const float*)d_in[1];
    const float* bias = (const float*)d_in[2];
    float* out = (float*)d_out;

    const int N = in_sizes[2];              // 4096
    const int K = in_sizes[1] / N;          // 4096
    const int M = in_sizes[0] / K;          // 16384

    ushort_t* xd = (ushort_t*)d_ws;                  // M*K bf16
    ushort_t* bt = xd + (size_t)M * K;               // N*K bf16
    // requires ws_size >= (M*K + N*K)*2 = 160 MB

    quant_x_kernel<<<(size_t)M * K / 2048, 256, 0, stream>>>(x, xd);
    quant_w_kernel<<<dim3(K / 64, N / 128), 256, 0, stream>>>(w, bt, K, N);
    gemm256_kernel<<<dim3((M / 256) * (N / 256)), 512, 0, stream>>>(
        xd, bt, bias, out, M, N, K);
}